// Round 17
// baseline (343.664 us; speedup 1.0000x reference)
//
#include <hip/hip_runtime.h>
#include <hip/hip_bf16.h>
#include <hip/hip_cooperative_groups.h>

// SelfAttention2D: b=8, c=512, hw=1024, groups=32, heads=8, d=64
// R17: single cooperative mega-kernel — 256 blocks x 512 thr (1/CU, 128KB
// LDS), 3 grid.sync() instead of 3 launch gaps (~15 µs measured by ledger).
// P1 gn(waves0-3)+wconv(waves4-7); P2 QK 128x128 + V 128x64 half-block tiles
// (512+512, perfectly balanced); P3 attn (R16 body per half-block);
// P4 proj (8-wave, tile=bid). Per-phase residency identical to R16.

namespace cg = cooperative_groups;

typedef __attribute__((ext_vector_type(8))) short short8v;
typedef __attribute__((ext_vector_type(4))) short short4v;
typedef __attribute__((ext_vector_type(4))) float f32x4;
typedef __attribute__((ext_vector_type(2))) unsigned uint2v;
typedef __attribute__((ext_vector_type(4))) unsigned uint4v;

constexpr int Bn = 8, Cn = 512, HWn = 1024;

#if __has_builtin(__builtin_amdgcn_exp2f)
#define EXP2F(x) __builtin_amdgcn_exp2f(x)
#else
#define EXP2F(x) __exp2f(x)
#endif

static __device__ __forceinline__ unsigned short bf16u(float f) {
  __hip_bfloat16 h = __float2bfloat16(f);
  return __builtin_bit_cast(unsigned short, h);
}
static __device__ __forceinline__ short bf16_of(float f) {
  return (short)bf16u(f);
}
static __device__ __forceinline__ unsigned bf16pk(float a, float b) {
  return (unsigned)bf16u(a) | ((unsigned)bf16u(b) << 16);
}
static __device__ __forceinline__ unsigned cvtpk(float lo, float hi) {
  unsigned r;
  asm("v_cvt_pk_bf16_f32 %0, %1, %2" : "=v"(r) : "v"(lo), "v"(hi));
  return r;
}
static __device__ __forceinline__ void gload16(const void* g, void* l) {
  __builtin_amdgcn_global_load_lds(
      (const __attribute__((address_space(1))) unsigned*)g,
      (__attribute__((address_space(3))) unsigned*)l, 16, 0, 0);
}
__device__ __forceinline__ short8v frag64(const short* buf, int row, int gk) {
  return *(const short8v*)&buf[row * 64 + ((gk ^ (row & 7)) << 3)];
}
__device__ __forceinline__ short8v frag128(const short* buf, int row, int gk) {
  return *(const short8v*)&buf[row * 128 + ((gk ^ (row & 7)) << 3)];
}

__global__ __launch_bounds__(512, 2) void mega_k(
    const float* __restrict__ x, const float* __restrict__ gw,
    const float* __restrict__ gb, const float* __restrict__ wq,
    const float* __restrict__ wp, const float* __restrict__ qkv_b,
    const float* __restrict__ proj_b, float* __restrict__ out,
    short* __restrict__ wqb, short* __restrict__ wpb,
    short* __restrict__ xn3, short* __restrict__ qT,
    short* __restrict__ kT, short* __restrict__ vB,
    short* __restrict__ aoT) {
  cg::grid_group gridg = cg::this_grid();
  __shared__ __align__(16) short smem[65536];  // 131072 B
  __shared__ float rs[8], rss[8];
  const int bid = blockIdx.x;          // 0..255
  const int t5 = threadIdx.x;          // 0..511
  const int grp = t5 >> 8;             // half-block 0/1 (waves 0-3 / 4-7)
  const int tg = t5 & 255;             // thread within half-block
  const f32x4 vzero = {0.f, 0.f, 0.f, 0.f};

  // ================= P1: GroupNorm (grp0) + weight cast (grp1) ==============
  {
    f32x4 v[16];
    const int g = bid & 31;
    if (grp == 1) {
#pragma unroll
      for (int u = 0; u < 4; u++) {
        int i = bid * 1024 + u * 256 + tg;  // f32x4 index, 262144 total
        const float* src = wq;
        short* dst = wqb;
        int idx = i;
        if (i >= 196608) { src = wp; dst = wpb; idx = i - 196608; }
        f32x4 vv = ((const f32x4*)src)[idx];
        short4v o;
        o.x = bf16_of(vv.x); o.y = bf16_of(vv.y);
        o.z = bf16_of(vv.z); o.w = bf16_of(vv.w);
        *(short4v*)&dst[idx * 4] = o;
      }
    } else {
      const f32x4* src = (const f32x4*)(x + (size_t)bid * 16384);
      float s = 0.f, ss = 0.f;
#pragma unroll
      for (int k = 0; k < 16; k++) {
        v[k] = src[tg + 256 * k];  // c = k, hw = 4*tg..4*tg+3
        s += v[k].x + v[k].y + v[k].z + v[k].w;
        ss += v[k].x * v[k].x + v[k].y * v[k].y + v[k].z * v[k].z + v[k].w * v[k].w;
      }
#pragma unroll
      for (int off = 32; off; off >>= 1) {
        s += __shfl_xor(s, off);
        ss += __shfl_xor(ss, off);
      }
      if ((tg & 63) == 0) { rs[tg >> 6] = s; rss[tg >> 6] = ss; }
    }
    __syncthreads();
    if (grp == 0) {
      const float S = rs[0] + rs[1] + rs[2] + rs[3];
      const float SS = rss[0] + rss[1] + rss[2] + rss[3];
      constexpr float invn = 1.0f / 16384.f;
      const float mu = S * invn;
      const float var = SS * invn - mu * mu;
      const float rstd = rsqrtf(var + 1e-5f);
      float ga[16], be[16];
#pragma unroll
      for (int k = 0; k < 16; k++) {
        ga[k] = gw[g * 16 + k] * rstd;
        be[k] = gb[g * 16 + k] - mu * ga[k];
      }
      short* dst = xn3 + (size_t)bid * 16384;  // panel [1024 hw][16 c]
#pragma unroll
      for (int d = 0; d < 4; d++) {
        unsigned pk[8];
#pragma unroll
        for (int k = 0; k < 16; k += 2)
          pk[k >> 1] = bf16pk(fmaf(v[k][d], ga[k], be[k]),
                              fmaf(v[k + 1][d], ga[k + 1], be[k + 1]));
        uint4v lo = {pk[0], pk[1], pk[2], pk[3]};
        uint4v hi = {pk[4], pk[5], pk[6], pk[7]};
        *(uint4v*)&dst[(4 * tg + d) * 16] = lo;
        *(uint4v*)&dst[(4 * tg + d) * 16 + 8] = hi;
      }
    }
  }
  __threadfence();
  gridg.sync();

  // ================= P2a: QK GEMM, 128x128 half-block tiles (512) ===========
  {
    const int hs = bid * 2 + grp;
    const int bn = hs & 7, bm = (hs >> 3) & 7, b = hs >> 6;
    const int m0 = bm * 128, n0 = bn * 128;  // m0 < 1024: Q/K only
    const short* Bb = xn3 + (size_t)b * 524288;
    short* As = smem + grp * 32768;  // [2][8192]
    short* Bs = As + 16384;          // [2][8192]
    const int t = tg, l = t & 63, w = t >> 6;
    const int wr = w >> 1, wc = w & 1;
    f32x4 acc[4][4];
#pragma unroll
    for (int i = 0; i < 4; i++)
#pragma unroll
      for (int j = 0; j < 4; j++) acc[i][j] = vzero;
    const int sr0 = t >> 3, sg = t & 7;

    // stage K-step k0 into buffer buf
    auto stage = [&](int buf, int k0) {
#pragma unroll
      for (int it = 0; it < 4; it++) {
        int r = it * 32 + sr0;
        int gs = sg ^ (r & 7);
        gload16(&wqb[(size_t)(m0 + r) * 512 + k0 + gs * 8],
                &As[buf * 8192 + it * 2048 + w * 512]);
        int gp = (k0 >> 4) + (gs >> 1);
        gload16(&Bb[(size_t)((gp << 10) + n0 + r) * 16 + ((gs & 1) << 3)],
                &Bs[buf * 8192 + it * 2048 + w * 512]);
      }
    };
    stage(0, 0);
    __syncthreads();
    for (int ks = 0; ks < 8; ks++) {
      const int cb = ks & 1;
      if (ks < 7) stage(cb ^ 1, (ks + 1) * 64);
#pragma unroll
      for (int kk = 0; kk < 2; kk++) {
        short8v af[4], bf[4];
#pragma unroll
        for (int i = 0; i < 4; i++)
          af[i] = frag64(As + cb * 8192, wr * 64 + i * 16 + (l & 15), kk * 4 + (l >> 4));
#pragma unroll
        for (int j = 0; j < 4; j++)
          bf[j] = frag64(Bs + cb * 8192, wc * 64 + j * 16 + (l & 15), kk * 4 + (l >> 4));
#pragma unroll
        for (int i = 0; i < 4; i++)
#pragma unroll
          for (int j = 0; j < 4; j++)
            acc[i][j] = __builtin_amdgcn_mfma_f32_16x16x32_bf16(af[i], bf[j], acc[i][j], 0, 0, 0);
      }
      __syncthreads();
    }
    short* oBase = (m0 < 512) ? qT : kT;
    const int mc = (m0 < 512 ? m0 : m0 - 512) + wr * 64;
#pragma unroll
    for (int i = 0; i < 4; i++) {
      int mi = mc + i * 16 + (l >> 4) * 4;
      f32x4 bv = *(const f32x4*)&qkv_b[m0 + wr * 64 + i * 16 + (l >> 4) * 4];
#pragma unroll
      for (int j = 0; j < 4; j++) {
        int n = n0 + wc * 64 + j * 16 + (l & 15);
        uint2v pk = {bf16pk(acc[i][j][0] + bv[0], acc[i][j][1] + bv[1]),
                     bf16pk(acc[i][j][2] + bv[2], acc[i][j][3] + bv[3])};
        *(uint2v*)&oBase[((size_t)b * HWn + n) * 512 + mi] = pk;
      }
    }
  }

  // ================= P2b: V GEMM, 128x64 half-block tiles (512) =============
  {
    const int hs = bid * 2 + grp;
    const int bn = hs & 15, bm = (hs >> 4) & 3, b = hs >> 6;
    const int m0 = 1024 + bm * 128, n0 = bn * 64;
    const short* Bb = xn3 + (size_t)b * 524288;
    short* As = smem + grp * 32768;  // [2][8192]
    short* Bs = As + 16384;          // [2][4096]
    const int t = tg, l = t & 63, w = t >> 6;
    const int wr = w >> 1, wc = w & 1;
    f32x4 acc[4][2];
#pragma unroll
    for (int i = 0; i < 4; i++)
#pragma unroll
      for (int j = 0; j < 2; j++) acc[i][j] = vzero;
    const int sr0 = t >> 3, sg = t & 7;

    auto stageV = [&](int buf, int k0) {
#pragma unroll
      for (int it = 0; it < 4; it++) {  // A: 128 rows
        int r = it * 32 + sr0;
        int gs = sg ^ (r & 7);
        gload16(&wqb[(size_t)(m0 + r) * 512 + k0 + gs * 8],
                &As[buf * 8192 + it * 2048 + w * 512]);
      }
#pragma unroll
      for (int it = 0; it < 2; it++) {  // B: 64 rows (n), 64 cols (k)
        int r = it * 32 + sr0;
        int gs = sg ^ (r & 7);
        int gp = (k0 >> 4) + (gs >> 1);
        gload16(&Bb[(size_t)((gp << 10) + n0 + r) * 16 + ((gs & 1) << 3)],
                &Bs[buf * 4096 + it * 2048 + w * 512]);
      }
    };
    stageV(0, 0);
    __syncthreads();
    for (int ks = 0; ks < 8; ks++) {
      const int cb = ks & 1;
      if (ks < 7) stageV(cb ^ 1, (ks + 1) * 64);
#pragma unroll
      for (int kk = 0; kk < 2; kk++) {
        short8v af[4], bf[2];
#pragma unroll
        for (int i = 0; i < 4; i++)
          af[i] = frag64(As + cb * 8192, wr * 64 + i * 16 + (l & 15), kk * 4 + (l >> 4));
#pragma unroll
        for (int j = 0; j < 2; j++)
          bf[j] = frag64(Bs + cb * 4096, wc * 32 + j * 16 + (l & 15), kk * 4 + (l >> 4));
#pragma unroll
        for (int i = 0; i < 4; i++)
#pragma unroll
          for (int j = 0; j < 2; j++)
            acc[i][j] = __builtin_amdgcn_mfma_f32_16x16x32_bf16(bf[j], af[i], acc[i][j], 0, 0, 0);
      }
      __syncthreads();
    }
#pragma unroll
    for (int i = 0; i < 4; i++) {
      int m = m0 + wr * 64 + i * 16 + (l & 15);
      float bv = qkv_b[m];
      short* vrow = vB + ((size_t)b * 512 + (m - 1024)) * HWn;
#pragma unroll
      for (int j = 0; j < 2; j++) {
        int n = n0 + wc * 32 + j * 16 + (l >> 4) * 4;
        uint2v pk = {bf16pk(acc[i][j][0] + bv, acc[i][j][1] + bv),
                     bf16pk(acc[i][j][2] + bv, acc[i][j][3] + bv)};
        *(uint2v*)&vrow[n] = pk;
      }
    }
  }
  __threadfence();
  gridg.sync();

  // ================= P3: attention, half-block tiles (512) ==================
  {
    const int hs = bid * 2 + grp;
    const int qt = hs & 7, head = (hs >> 3) & 7, b = hs >> 6;
    short* SM = smem + grp * 32768;  // 64KB per half-block
    const int t = tg, l = t & 63, w = t >> 6;
    const int g = l >> 4;

    const short* ksrc = kT + (size_t)b * HWn * 512 + head * 64;
    const short* vsrc = vB + ((size_t)b * 512 + head * 64) * HWn;

    const short* qbase = qT +
        ((size_t)b * HWn + qt * 128 + 32 * w + (l & 15)) * 512 + head * 64 + g * 8;
    const short8v qA0 = *(const short8v*)&qbase[0];
    const short8v qA1 = *(const short8v*)&qbase[32];
    const short8v qB0 = *(const short8v*)&qbase[16 * 512];
    const short8v qB1 = *(const short8v*)&qbase[16 * 512 + 32];

    const int kkv0 = w * 8 + (l >> 3), kg = l & 7;
    const int vd0 = w * 4 + (l >> 4), vg = l & 15;

    auto stageKV = [&](int bp, int kt_) {
#pragma unroll
      for (int it = 0; it < 4; it++) {
        int kv = kkv0 + it * 32;
        gload16(&ksrc[(size_t)(kt_ * 128 + kv) * 512 + (kg ^ (kv & 7)) * 8],
                &SM[bp + it * 2048 + w * 512]);
        int d = vd0 + it * 16;
        gload16(&vsrc[(size_t)d * HWn + kt_ * 128 + (vg ^ (d & 7)) * 8],
                &SM[bp + 8192 + it * 2048 + w * 512]);
      }
    };
    stageKV(0, 0);
    __syncthreads();

    f32x4 oaA[4], oaB[4];
#pragma unroll
    for (int f = 0; f < 4; f++) { oaA[f] = vzero; oaB[f] = vzero; }
    float lA = 0.f, lB = 0.f;
    constexpr float SC = 0.1803368801111f;
    constexpr float MOFF = -11.5415602855f;

#pragma unroll 1
    for (int kt = 0; kt < 8; kt++) {
      const int cb = (kt & 1) * 16384;
      if (kt < 7) stageKV(cb ^ 16384, kt + 1);
      const short* Ks = SM + cb;
      const short* Vs = SM + cb + 8192;

      f32x4 saA[8], saB[8];
      __builtin_amdgcn_s_setprio(1);
#pragma unroll
      for (int f = 0; f < 8; f++) {
        short8v ka0 = frag64(Ks, 16 * f + (l & 15), g);
        short8v ka1 = frag64(Ks, 16 * f + (l & 15), g + 4);
        saA[f] = __builtin_amdgcn_mfma_f32_16x16x32_bf16(ka0, qA0, vzero, 0, 0, 0);
        saB[f] = __builtin_amdgcn_mfma_f32_16x16x32_bf16(ka0, qB0, vzero, 0, 0, 0);
        saA[f] = __builtin_amdgcn_mfma_f32_16x16x32_bf16(ka1, qA1, saA[f], 0, 0, 0);
        saB[f] = __builtin_amdgcn_mfma_f32_16x16x32_bf16(ka1, qB1, saB[f], 0, 0, 0);
      }
      __builtin_amdgcn_s_setprio(0);

      f32x4 psAv = vzero, psBv = vzero;
#pragma unroll
      for (int f = 0; f < 8; f++)
#pragma unroll
        for (int r = 0; r < 4; r++) {
          float eA = EXP2F(fmaf(saA[f][r], SC, MOFF));
          float eB = EXP2F(fmaf(saB[f][r], SC, MOFF));
          saA[f][r] = eA;
          saB[f][r] = eB;
          psAv[r] += eA;
          psBv[r] += eB;
        }
      float psA = (psAv[0] + psAv[1]) + (psAv[2] + psAv[3]);
      float psB = (psBv[0] + psBv[1]) + (psBv[2] + psBv[3]);
      psA += __shfl_xor(psA, 16);
      psA += __shfl_xor(psA, 32);
      psB += __shfl_xor(psB, 16);
      psB += __shfl_xor(psB, 32);
      lA += psA;
      lB += psB;

      short8v paA[4], paB[4];
#pragma unroll
      for (int c = 0; c < 4; c++) {
        unsigned A0 = cvtpk(saA[2 * c][0], saA[2 * c][1]);
        unsigned A1 = cvtpk(saA[2 * c][2], saA[2 * c][3]);
        unsigned B0 = cvtpk(saA[2 * c + 1][0], saA[2 * c + 1][1]);
        unsigned B1 = cvtpk(saA[2 * c + 1][2], saA[2 * c + 1][3]);
        uint2v p0 = __builtin_amdgcn_permlane32_swap(A0, B0, false, false);
        uint2v p1 = __builtin_amdgcn_permlane32_swap(A1, B1, false, false);
        uint2v q0 = __builtin_amdgcn_permlane16_swap(p0[0], p0[1], false, false);
        uint2v q1 = __builtin_amdgcn_permlane16_swap(p1[0], p1[1], false, false);
        uint4v ua = {q0[0], q1[0], q0[1], q1[1]};
        paA[c] = __builtin_bit_cast(short8v, ua);

        unsigned C0 = cvtpk(saB[2 * c][0], saB[2 * c][1]);
        unsigned C1 = cvtpk(saB[2 * c][2], saB[2 * c][3]);
        unsigned D0 = cvtpk(saB[2 * c + 1][0], saB[2 * c + 1][1]);
        unsigned D1 = cvtpk(saB[2 * c + 1][2], saB[2 * c + 1][3]);
        uint2v p2 = __builtin_amdgcn_permlane32_swap(C0, D0, false, false);
        uint2v p3 = __builtin_amdgcn_permlane32_swap(C1, D1, false, false);
        uint2v q2 = __builtin_amdgcn_permlane16_swap(p2[0], p2[1], false, false);
        uint2v q3 = __builtin_amdgcn_permlane16_swap(p3[0], p3[1], false, false);
        uint4v ub = {q2[0], q3[0], q2[1], q3[1]};
        paB[c] = __builtin_bit_cast(short8v, ub);
      }

      __builtin_amdgcn_s_setprio(1);
#pragma unroll
      for (int fd = 0; fd < 4; fd++) {
        int row = 16 * fd + (l & 15);
#pragma unroll
        for (int c = 0; c < 4; c++) {
          short8v vb = frag128(Vs, row, c * 4 + g);
          oaA[fd] = __builtin_amdgcn_mfma_f32_16x16x32_bf16(paA[c], vb, oaA[fd], 0, 0, 0);
          oaB[fd] = __builtin_amdgcn_mfma_f32_16x16x32_bf16(paB[c], vb, oaB[fd], 0, 0, 0);
        }
      }
      __builtin_amdgcn_s_setprio(0);

      if (kt < 7) __syncthreads();
    }

    const float invA = 1.0f / lA, invB = 1.0f / lB;
    float ivA[4], ivB[4];
#pragma unroll
    for (int r = 0; r < 4; r++) {
      ivA[r] = __shfl(invA, 4 * g + r);
      ivB[r] = __shfl(invB, 4 * g + r);
    }
    __syncthreads();  // all waves done with final tile; SM reusable
    short* PsA = SM + (2 * w) * 2176;
    short* PsB = SM + (2 * w + 1) * 2176;
#pragma unroll
    for (int r = 0; r < 4; r++)
#pragma unroll
      for (int f = 0; f < 4; f++) {
        PsA[(4 * g + r) * 136 + 16 * f + (l & 15)] = bf16_of(oaA[f][r] * ivA[r]);
        PsB[(4 * g + r) * 136 + 16 * f + (l & 15)] = bf16_of(oaB[f][r] * ivB[r]);
      }
    __syncthreads();
    short* dst = aoT + ((size_t)b * HWn + qt * 128) * 512 + head * 64;
#pragma unroll
    for (int it = 0; it < 4; it++) {
      int r = (t >> 3) + 32 * it;
      int c8 = (t & 7) * 8;
      *(short8v*)&dst[(size_t)r * 512 + c8] =
          *(const short8v*)&SM[(r >> 4) * 2176 + (r & 15) * 136 + c8];
    }
  }
  __threadfence();
  gridg.sync();

  // ================= P4: proj GEMM, 8-wave 128x128 tiles (256) ==============
  {
    const int bn = bid & 7, bm = (bid >> 3) & 3, b = bid >> 5;
    const short* Bb = aoT + (size_t)b * HWn * Cn;
    short* As = smem;          // [2][8192]
    short* Bs = smem + 16384;  // [2][8192]
    const int t = t5, l = t & 63, w = t >> 6;  // w 0..7
    const int wr = w >> 1, wc = w & 1;
    const int m0 = bm * 128, n0 = bn * 128;
    f32x4 acc[2][4];
#pragma unroll
    for (int i = 0; i < 2; i++)
#pragma unroll
      for (int j = 0; j < 4; j++) acc[i][j] = vzero;
    const int sr0 = t >> 3, sg = t & 7;  // sr0 0..63

    auto stageP = [&](int buf, int k0) {
#pragma unroll
      for (int it = 0; it < 2; it++) {
        int r = it * 64 + sr0;
        int gs = sg ^ (r & 7);
        gload16(&wpb[(size_t)(m0 + r) * 512 + k0 + gs * 8],
                &As[buf * 8192 + it * 4096 + w * 512]);
        gload16(&Bb[(size_t)(n0 + r) * 512 + k0 + gs * 8],
                &Bs[buf * 8192 + it * 4096 + w * 512]);
      }
    };
    stageP(0, 0);
    __syncthreads();
    for (int ks = 0; ks < 8; ks++) {
      const int cb = ks & 1;
      if (ks < 7) stageP(cb ^ 1, (ks + 1) * 64);
#pragma unroll
      for (int kk = 0; kk < 2; kk++) {
        short8v af[2], bf[4];
#pragma unroll
        for (int i = 0; i < 2; i++)
          af[i] = frag64(As + cb * 8192, wr * 32 + i * 16 + (l & 15), kk * 4 + (l >> 4));
#pragma unroll
        for (int j = 0; j < 4; j++)
          bf[j] = frag64(Bs + cb * 8192, wc * 64 + j * 16 + (l & 15), kk * 4 + (l >> 4));
#pragma unroll
        for (int i = 0; i < 2; i++)
#pragma unroll
          for (int j = 0; j < 4; j++)
            acc[i][j] = __builtin_amdgcn_mfma_f32_16x16x32_bf16(af[i], bf[j], acc[i][j], 0, 0, 0);
      }
      __syncthreads();
    }
    float* outb = out + (size_t)b * Cn * HWn;
    const float* rb = x + (size_t)b * Cn * HWn;
#pragma unroll
    for (int i = 0; i < 2; i++) {
      f32x4 bv = *(const f32x4*)&proj_b[m0 + wr * 32 + i * 16 + (l >> 4) * 4];
#pragma unroll
      for (int r = 0; r < 4; r++) {
        int m = m0 + wr * 32 + i * 16 + (l >> 4) * 4 + r;
#pragma unroll
        for (int j = 0; j < 4; j++) {
          int n = n0 + wc * 64 + j * 16 + (l & 15);
          size_t idx = (size_t)m * HWn + n;
          outb[idx] = acc[i][j][r] + bv[r] + rb[idx];
        }
      }
    }
  }
}

extern "C" void kernel_launch(void* const* d_in, const int* in_sizes, int n_in,
                              void* d_out, int out_size, void* d_ws, size_t ws_size,
                              hipStream_t stream) {
  const float* x = (const float*)d_in[0];
  const float* gn_w = (const float*)d_in[1];
  const float* gn_b = (const float*)d_in[2];
  const float* qkv_w = (const float*)d_in[3];
  const float* qkv_b = (const float*)d_in[4];
  const float* proj_w = (const float*)d_in[5];
  const float* proj_b = (const float*)d_in[6];
  float* out = (float*)d_out;

  char* ws = (char*)d_ws;
  short* wqb = (short*)(ws + 4096);            // 1536*512
  short* wpb = (short*)(ws + 4096 + 1572864);  // 512*512
  char* p = ws + 4096 + 1572864 + 524288;
  const size_t SB = (size_t)Bn * HWn * 512 * 2;  // 8 MB
  short* xn3 = (short*)p;
  short* qT = (short*)(p + SB);
  short* kT = (short*)(p + 2 * SB);
  short* vB = (short*)(p + 3 * SB);
  short* aoT = (short*)(p + 4 * SB);

  void* args[] = {(void*)&x,      (void*)&gn_w,   (void*)&gn_b,
                  (void*)&qkv_w,  (void*)&proj_w, (void*)&qkv_b,
                  (void*)&proj_b, (void*)&out,    (void*)&wqb,
                  (void*)&wpb,    (void*)&xn3,    (void*)&qT,
                  (void*)&kT,     (void*)&vB,     (void*)&aoT};
  hipLaunchCooperativeKernel((const void*)mega_k, dim3(256), dim3(512), args,
                             0, stream);
}

// Round 18
// 75.207 us; speedup vs baseline: 4.5696x; 4.5696x over previous
//
#include <hip/hip_runtime.h>
#include <hip/hip_bf16.h>

// SelfAttention2D: b=8, c=512, hw=1024, groups=32, heads=8, d=64
// R18: revert to R15 (best measured, 75.300 µs). R17's cooperative mega-kernel
// collapsed occupancy (128KB LDS -> 1 block/CU, grid.sync spin) -> 343 µs.
// Pipeline: gn_fused -> qkv GEMM (dbuf) -> attn (P-in-reg via cvt_pk+permlane,
// T14 reg prefetch) -> proj GEMM (dbuf, 8-wave).

typedef __attribute__((ext_vector_type(8))) short short8v;
typedef __attribute__((ext_vector_type(4))) short short4v;
typedef __attribute__((ext_vector_type(4))) float f32x4;
typedef __attribute__((ext_vector_type(2))) unsigned uint2v;
typedef __attribute__((ext_vector_type(4))) unsigned uint4v;

constexpr int Bn = 8, Cn = 512, HWn = 1024;

#if __has_builtin(__builtin_amdgcn_exp2f)
#define EXP2F(x) __builtin_amdgcn_exp2f(x)
#else
#define EXP2F(x) __exp2f(x)
#endif

static __device__ __forceinline__ unsigned short bf16u(float f) {
  __hip_bfloat16 h = __float2bfloat16(f);  // native v_cvt on gfx950
  return __builtin_bit_cast(unsigned short, h);
}
static __device__ __forceinline__ short bf16_of(float f) {
  return (short)bf16u(f);
}
static __device__ __forceinline__ unsigned bf16pk(float a, float b) {
  return (unsigned)bf16u(a) | ((unsigned)bf16u(b) << 16);
}
static __device__ __forceinline__ unsigned cvtpk(float lo, float hi) {
  unsigned r;
  asm("v_cvt_pk_bf16_f32 %0, %1, %2" : "=v"(r) : "v"(lo), "v"(hi));
  return r;
}

// async global->LDS, 16B/lane; LDS dest wave-uniform base + lane*16B.
static __device__ __forceinline__ void gload16(const void* g, void* l) {
  __builtin_amdgcn_global_load_lds(
      (const __attribute__((address_space(1))) unsigned*)g,
      (__attribute__((address_space(3))) unsigned*)l, 16, 0, 0);
}

// ---------------- fused GroupNorm (blocks 0..255) + weight cast (256..1279) --
__global__ __launch_bounds__(256) void gn_fused_k(const float* __restrict__ x,
                                                  const float* __restrict__ gw,
                                                  const float* __restrict__ gb,
                                                  const float* __restrict__ wq,
                                                  const float* __restrict__ wp,
                                                  short* __restrict__ oq,
                                                  short* __restrict__ op,
                                                  short* __restrict__ xn3) {
  const int t = threadIdx.x;
  if (blockIdx.x >= 256) {
    int i = (blockIdx.x - 256) * 256 + t;  // f32x4 index, 262144 total
    const float* src = wq;
    short* dst = oq;
    int idx = i;
    if (i >= 196608) { src = wp; dst = op; idx = i - 196608; }
    f32x4 v = ((const f32x4*)src)[idx];
    short4v o;
    o.x = bf16_of(v.x); o.y = bf16_of(v.y); o.z = bf16_of(v.z); o.w = bf16_of(v.w);
    *(short4v*)&dst[idx * 4] = o;
    return;
  }
  const int bg = blockIdx.x;  // b*32 + g
  const int g = bg & 31;
  const f32x4* src = (const f32x4*)(x + (size_t)bg * 16384);
  f32x4 v[16];
  float s = 0.f, ss = 0.f;
#pragma unroll
  for (int k = 0; k < 16; k++) {
    v[k] = src[t + 256 * k];  // c = k, hw = 4t..4t+3
    s += v[k].x + v[k].y + v[k].z + v[k].w;
    ss += v[k].x * v[k].x + v[k].y * v[k].y + v[k].z * v[k].z + v[k].w * v[k].w;
  }
#pragma unroll
  for (int off = 32; off; off >>= 1) {
    s += __shfl_xor(s, off);
    ss += __shfl_xor(ss, off);
  }
  __shared__ float rs[4], rss[4];
  const int lane = t & 63, w = t >> 6;
  if (lane == 0) { rs[w] = s; rss[w] = ss; }
  __syncthreads();
  const float S = rs[0] + rs[1] + rs[2] + rs[3];
  const float SS = rss[0] + rss[1] + rss[2] + rss[3];
  constexpr float invn = 1.0f / 16384.f;
  const float mu = S * invn;
  const float var = SS * invn - mu * mu;
  const float rstd = rsqrtf(var + 1e-5f);
  float ga[16], be[16];
#pragma unroll
  for (int k = 0; k < 16; k++) {
    ga[k] = gw[g * 16 + k] * rstd;
    be[k] = gb[g * 16 + k] - mu * ga[k];
  }
  short* dst = xn3 + (size_t)bg * 16384;  // panel [1024 hw][16 c]
#pragma unroll
  for (int d = 0; d < 4; d++) {  // hw = 4t + d
    unsigned pk[8];
#pragma unroll
    for (int k = 0; k < 16; k += 2)
      pk[k >> 1] = bf16pk(fmaf(v[k][d], ga[k], be[k]),
                          fmaf(v[k + 1][d], ga[k + 1], be[k + 1]));
    uint4v lo = {pk[0], pk[1], pk[2], pk[3]};
    uint4v hi = {pk[4], pk[5], pk[6], pk[7]};
    *(uint4v*)&dst[(4 * t + d) * 16] = lo;
    *(uint4v*)&dst[(4 * t + d) * 16 + 8] = hi;
  }
}

// ---------------- fragment read: row stride 64/128, XOR(row&7) swizzle ------
__device__ __forceinline__ short8v frag64(const short* buf, int row, int gk) {
  return *(const short8v*)&buf[row * 64 + ((gk ^ (row & 7)) << 3)];
}
__device__ __forceinline__ short8v frag128(const short* buf, int row, int gk) {
  return *(const short8v*)&buf[row * 128 + ((gk ^ (row & 7)) << 3)];
}

// ---------------- qkv GEMM: 128x128 tile, BK=64, double-buffered, (256,2) ---
__global__ __launch_bounds__(256, 2) void gemm_qkv_k(
    const short* __restrict__ A, const short* __restrict__ xn3,
    const float* __restrict__ bias, short* __restrict__ oQ,
    short* __restrict__ oK, short* __restrict__ oV) {
  const int bid = blockIdx.x;
  const int swz = (bid & 7) * 96 + (bid >> 3);
  const int bn = swz & 7;
  const int rest = swz >> 3;
  const int bm = rest % 12, b = rest / 12;
  const bool VBLK = (bm >= 8);

  const short* Bb = xn3 + (size_t)b * 524288;  // 32 panels x [1024][16]
  __shared__ __align__(16) short As[2][8192];
  __shared__ __align__(16) short Bs[2][8192];
  const int t = threadIdx.x, l = t & 63, w = t >> 6;
  const int wr = w >> 1, wc = w & 1;
  const int m0 = bm * 128, n0 = bn * 128;
  const f32x4 vzero = {0.f, 0.f, 0.f, 0.f};
  f32x4 acc[4][4];
#pragma unroll
  for (int i = 0; i < 4; i++)
#pragma unroll
    for (int j = 0; j < 4; j++) acc[i][j] = vzero;

  const int sr0 = t >> 3;  // + it*32
  const int sg = t & 7;

#define STAGE_QKV(buf, k0)                                                    \
  do {                                                                        \
    _Pragma("unroll") for (int it = 0; it < 4; it++) {                        \
      int r = it * 32 + sr0;                                                  \
      int gs = sg ^ (r & 7);                                                  \
      gload16(&A[(size_t)(m0 + r) * 512 + (k0) + gs * 8],                     \
              &As[buf][it * 2048 + w * 512]);                                 \
      int gp = ((k0) >> 4) + (gs >> 1);                                       \
      gload16(&Bb[(size_t)((gp << 10) + n0 + r) * 16 + ((gs & 1) << 3)],      \
              &Bs[buf][it * 2048 + w * 512]);                                 \
    }                                                                         \
  } while (0)

  STAGE_QKV(0, 0);
  __syncthreads();

  for (int ks = 0; ks < 8; ks++) {
    const int cb = ks & 1;
    if (ks < 7) STAGE_QKV(cb ^ 1, (ks + 1) * 64);  // in flight during compute
#pragma unroll
    for (int kk = 0; kk < 2; kk++) {
      short8v af[4], bf[4];
#pragma unroll
      for (int i = 0; i < 4; i++)
        af[i] = frag64(&As[cb][0], wr * 64 + i * 16 + (l & 15), kk * 4 + (l >> 4));
#pragma unroll
      for (int j = 0; j < 4; j++)
        bf[j] = frag64(&Bs[cb][0], wc * 64 + j * 16 + (l & 15), kk * 4 + (l >> 4));
      if (VBLK) {
#pragma unroll
        for (int i = 0; i < 4; i++)
#pragma unroll
          for (int j = 0; j < 4; j++)
            acc[i][j] = __builtin_amdgcn_mfma_f32_16x16x32_bf16(bf[j], af[i], acc[i][j], 0, 0, 0);
      } else {
#pragma unroll
        for (int i = 0; i < 4; i++)
#pragma unroll
          for (int j = 0; j < 4; j++)
            acc[i][j] = __builtin_amdgcn_mfma_f32_16x16x32_bf16(af[i], bf[j], acc[i][j], 0, 0, 0);
      }
    }
    __syncthreads();  // drains prefetch vmcnt; cb fully consumed
  }

  if (!VBLK) {
    short* oBase = (m0 < 512) ? oQ : oK;
    const int mc = (m0 < 512 ? m0 : m0 - 512) + wr * 64;
#pragma unroll
    for (int i = 0; i < 4; i++) {
      int mi = mc + i * 16 + (l >> 4) * 4;
      f32x4 bv = *(const f32x4*)&bias[m0 + wr * 64 + i * 16 + (l >> 4) * 4];
#pragma unroll
      for (int j = 0; j < 4; j++) {
        int n = n0 + wc * 64 + j * 16 + (l & 15);
        uint2v pk = {bf16pk(acc[i][j][0] + bv[0], acc[i][j][1] + bv[1]),
                     bf16pk(acc[i][j][2] + bv[2], acc[i][j][3] + bv[3])};
        *(uint2v*)&oBase[((size_t)b * HWn + n) * 512 + mi] = pk;
      }
    }
  } else {
#pragma unroll
    for (int i = 0; i < 4; i++) {
      int m = m0 + wr * 64 + i * 16 + (l & 15);
      float bv = bias[m];
      short* vrow = oV + ((size_t)b * 512 + (m - 1024)) * HWn;
#pragma unroll
      for (int j = 0; j < 4; j++) {
        int n = n0 + wc * 64 + j * 16 + (l >> 4) * 4;
        uint2v pk = {bf16pk(acc[i][j][0] + bv, acc[i][j][1] + bv),
                     bf16pk(acc[i][j][2] + bv, acc[i][j][3] + bv)};
        *(uint2v*)&vrow[n] = pk;
      }
    }
  }
}

// ---------------- proj GEMM: 128x128 tile, 8 waves, BK=64, double-buffered --
__global__ __launch_bounds__(512, 2) void gemm_proj_k(
    const short* __restrict__ A, const short* __restrict__ Bt,
    const float* __restrict__ bias, const float* __restrict__ resid,
    float* __restrict__ outF) {
  const int bid = blockIdx.x;
  const int swz = (bid & 7) * 32 + (bid >> 3);
  const int bn = swz & 7;
  const int rest = swz >> 3;
  const int bm = rest & 3, b = rest >> 2;

  const short* Bb = Bt + (size_t)b * HWn * Cn;
  __shared__ __align__(16) short As[2][8192];
  __shared__ __align__(16) short Bs[2][8192];
  const int t = threadIdx.x, l = t & 63, w = t >> 6;
  const int wr = w >> 1, wc = w & 1;
  const int m0 = bm * 128, n0 = bn * 128;
  const f32x4 vzero = {0.f, 0.f, 0.f, 0.f};
  f32x4 acc[2][4];
#pragma unroll
  for (int i = 0; i < 2; i++)
#pragma unroll
    for (int j = 0; j < 4; j++) acc[i][j] = vzero;

  const int sr0 = t >> 3;  // 0..63, + it*64
  const int sg = t & 7;

#define STAGE_PROJ(buf, k0)                                                   \
  do {                                                                        \
    _Pragma("unroll") for (int it = 0; it < 2; it++) {                        \
      int r = it * 64 + sr0;                                                  \
      int gs = sg ^ (r & 7);                                                  \
      gload16(&A[(size_t)(m0 + r) * 512 + (k0) + gs * 8],                     \
              &As[buf][it * 4096 + w * 512]);                                 \
      gload16(&Bb[(size_t)(n0 + r) * 512 + (k0) + gs * 8],                    \
              &Bs[buf][it * 4096 + w * 512]);                                 \
    }                                                                         \
  } while (0)

  STAGE_PROJ(0, 0);
  __syncthreads();

  for (int ks = 0; ks < 8; ks++) {
    const int cb = ks & 1;
    if (ks < 7) STAGE_PROJ(cb ^ 1, (ks + 1) * 64);
#pragma unroll
    for (int kk = 0; kk < 2; kk++) {
      short8v af[2], bf[4];
#pragma unroll
      for (int i = 0; i < 2; i++)
        af[i] = frag64(&As[cb][0], wr * 32 + i * 16 + (l & 15), kk * 4 + (l >> 4));
#pragma unroll
      for (int j = 0; j < 4; j++)
        bf[j] = frag64(&Bs[cb][0], wc * 64 + j * 16 + (l & 15), kk * 4 + (l >> 4));
#pragma unroll
      for (int i = 0; i < 2; i++)
#pragma unroll
        for (int j = 0; j < 4; j++)
          acc[i][j] = __builtin_amdgcn_mfma_f32_16x16x32_bf16(af[i], bf[j], acc[i][j], 0, 0, 0);
    }
    __syncthreads();
  }

  float* outb = outF + (size_t)b * Cn * HWn;
  const float* rb = resid + (size_t)b * Cn * HWn;
#pragma unroll
  for (int i = 0; i < 2; i++) {
    f32x4 bv = *(const f32x4*)&bias[m0 + wr * 32 + i * 16 + (l >> 4) * 4];
#pragma unroll
    for (int r = 0; r < 4; r++) {
      int m = m0 + wr * 32 + i * 16 + (l >> 4) * 4 + r;
#pragma unroll
      for (int j = 0; j < 4; j++) {
        int n = n0 + wc * 64 + j * 16 + (l & 15);
        size_t idx = (size_t)m * HWn + n;
        outb[idx] = acc[i][j][r] + bv[r] + rb[idx];
      }
    }
  }
}

// ---------------- MFMA flash attention: 32 q/wave, P in registers -----------
// 512 blocks, 256 thr = 4 waves; wave w owns q-rows [32w, 32w+32) as two
// 16-row sub-blocks A/B sharing every K/V fragment read. KVBLK=128, kt=8.
// T14 reg prefetch; fixed-max softmax; PV A-frags built in-register via
// cvt_pk_bf16_f32 + permlane32_swap + permlane16_swap (no P LDS round-trip).
__global__ __launch_bounds__(256, 2) void attn_k(const short* __restrict__ qT,
                                                 const short* __restrict__ kT,
                                                 const short* __restrict__ vB,
                                                 short* __restrict__ aoT) {
  const int bid = blockIdx.x;
  const int swz = (bid & 7) * 64 + (bid >> 3);
  const int qt = swz & 7, head = (swz >> 3) & 7, b = swz >> 6;
  __shared__ __align__(16) short SM[33792];  // K/V + O-staging region
  short* Ks = SM;            // [128][64] = 8192
  short* Vs = SM + 8192;     // [64][128] = 8192
  short* Ps = SM + 16384;    // epilogue O staging only (8 x [16][136])
  const int t = threadIdx.x, l = t & 63, w = t >> 6;  // w 0..3
  short* PsA = Ps + (2 * w) * 2176;
  short* PsB = Ps + (2 * w + 1) * 2176;
  const int g = l >> 4;
  const f32x4 vzero = {0.f, 0.f, 0.f, 0.f};

  const short* ksrc = kT + (size_t)b * HWn * 512 + head * 64;
  const short* vsrc = vB + ((size_t)b * 512 + head * 64) * HWn;

  // Q fragments: direct global loads; sub-block A rows 32w+(l&15), B +16
  const short* qbase = qT +
      ((size_t)b * HWn + qt * 128 + 32 * w + (l & 15)) * 512 + head * 64 + g * 8;
  const short8v qA0 = *(const short8v*)&qbase[0];
  const short8v qA1 = *(const short8v*)&qbase[32];
  const short8v qB0 = *(const short8v*)&qbase[16 * 512];
  const short8v qB1 = *(const short8v*)&qbase[16 * 512 + 32];

  const int kkv0 = w * 8 + (l >> 3), kg = l & 7;
  const int vd0 = w * 4 + (l >> 4), vg = l & 15;

  // prologue: tile 0 via async gload_lds
#pragma unroll
  for (int it = 0; it < 4; it++) {
    int kv = kkv0 + it * 32;
    gload16(&ksrc[(size_t)kv * 512 + (kg ^ (kv & 7)) * 8], &Ks[it * 2048 + w * 512]);
    int d = vd0 + it * 16;
    gload16(&vsrc[(size_t)d * HWn + (vg ^ (d & 7)) * 8], &Vs[it * 2048 + w * 512]);
  }
  __syncthreads();

  f32x4 oaA[4], oaB[4];
#pragma unroll
  for (int f = 0; f < 4; f++) { oaA[f] = vzero; oaB[f] = vzero; }
  float lA = 0.f, lB = 0.f;
  constexpr float SC = 0.1803368801111f;     // log2(e)/8
  constexpr float MOFF = -11.5415602855f;    // -8*log2(e): fixed softmax shift

#pragma unroll 1
  for (int kt = 0; kt < 8; kt++) {
    short8v kreg[4], vreg[4];
    if (kt < 7) {  // T14: issue next-tile loads into regs during compute
      const int kt1 = kt + 1;
#pragma unroll
      for (int it = 0; it < 4; it++) {
        int kv = kkv0 + it * 32;
        kreg[it] = *(const short8v*)&ksrc[(size_t)(kt1 * 128 + kv) * 512 +
                                          (kg ^ (kv & 7)) * 8];
        int d = vd0 + it * 16;
        vreg[it] = *(const short8v*)&vsrc[(size_t)d * HWn + kt1 * 128 +
                                          (vg ^ (d & 7)) * 8];
      }
    }

    // QK^T (S^T form): each K fragment pair read once, feeds both q-blocks
    f32x4 saA[8], saB[8];
    __builtin_amdgcn_s_setprio(1);
#pragma unroll
    for (int f = 0; f < 8; f++) {
      short8v ka0 = frag64(Ks, 16 * f + (l & 15), g);
      short8v ka1 = frag64(Ks, 16 * f + (l & 15), g + 4);
      saA[f] = __builtin_amdgcn_mfma_f32_16x16x32_bf16(ka0, qA0, vzero, 0, 0, 0);
      saB[f] = __builtin_amdgcn_mfma_f32_16x16x32_bf16(ka0, qB0, vzero, 0, 0, 0);
      saA[f] = __builtin_amdgcn_mfma_f32_16x16x32_bf16(ka1, qA1, saA[f], 0, 0, 0);
      saB[f] = __builtin_amdgcn_mfma_f32_16x16x32_bf16(ka1, qB1, saB[f], 0, 0, 0);
    }
    __builtin_amdgcn_s_setprio(0);

    // fixed-max softmax: P = exp2(s*SC + MOFF); 4-way sum trees
    f32x4 psAv = vzero, psBv = vzero;
#pragma unroll
    for (int f = 0; f < 8; f++)
#pragma unroll
      for (int r = 0; r < 4; r++) {
        float eA = EXP2F(fmaf(saA[f][r], SC, MOFF));
        float eB = EXP2F(fmaf(saB[f][r], SC, MOFF));
        saA[f][r] = eA;
        saB[f][r] = eB;
        psAv[r] += eA;
        psBv[r] += eB;
      }
    float psA = (psAv[0] + psAv[1]) + (psAv[2] + psAv[3]);
    float psB = (psBv[0] + psBv[1]) + (psBv[2] + psBv[3]);
    psA += __shfl_xor(psA, 16);
    psA += __shfl_xor(psA, 32);
    psB += __shfl_xor(psB, 16);
    psB += __shfl_xor(psB, 32);
    lA += psA;
    lB += psB;

    // PV A-fragments in-register (no LDS):
    // lane (q=l&15, g) holds P[q][16f+4g+r]; pa[c] needs P[q][32c+8g+e].
    // W[f][0]=cvtpk(r0,r1), W[f][1]=cvtpk(r2,r3); with A=W[2c], B=W[2c+1]:
    //   p32(A0,B0) -> X=[A0g0,A0g1,B0g0,B0g1], Y=[A0g2,A0g3,B0g2,B0g3]
    //   p16(X,Y)   -> d0=[A0g0,A0g2,B0g0,B0g2], d2=[A0g1,A0g3,B0g1,B0g3]
    // d1/d3 from (A1,B1). pa[c] dwords = {d0, d1, d2, d3}.
    short8v paA[4], paB[4];
#pragma unroll
    for (int c = 0; c < 4; c++) {
      unsigned A0 = cvtpk(saA[2 * c][0], saA[2 * c][1]);
      unsigned A1 = cvtpk(saA[2 * c][2], saA[2 * c][3]);
      unsigned B0 = cvtpk(saA[2 * c + 1][0], saA[2 * c + 1][1]);
      unsigned B1 = cvtpk(saA[2 * c + 1][2], saA[2 * c + 1][3]);
      uint2v p0 = __builtin_amdgcn_permlane32_swap(A0, B0, false, false);
      uint2v p1 = __builtin_amdgcn_permlane32_swap(A1, B1, false, false);
      uint2v q0 = __builtin_amdgcn_permlane16_swap(p0[0], p0[1], false, false);
      uint2v q1 = __builtin_amdgcn_permlane16_swap(p1[0], p1[1], false, false);
      uint4v ua = {q0[0], q1[0], q0[1], q1[1]};
      paA[c] = __builtin_bit_cast(short8v, ua);

      unsigned C0 = cvtpk(saB[2 * c][0], saB[2 * c][1]);
      unsigned C1 = cvtpk(saB[2 * c][2], saB[2 * c][3]);
      unsigned D0 = cvtpk(saB[2 * c + 1][0], saB[2 * c + 1][1]);
      unsigned D1 = cvtpk(saB[2 * c + 1][2], saB[2 * c + 1][3]);
      uint2v p2 = __builtin_amdgcn_permlane32_swap(C0, D0, false, false);
      uint2v p3 = __builtin_amdgcn_permlane32_swap(C1, D1, false, false);
      uint2v q2 = __builtin_amdgcn_permlane16_swap(p2[0], p2[1], false, false);
      uint2v q3 = __builtin_amdgcn_permlane16_swap(p3[0], p3[1], false, false);
      uint4v ub = {q2[0], q3[0], q2[1], q3[1]};
      paB[c] = __builtin_bit_cast(short8v, ub);
    }

    __builtin_amdgcn_s_setprio(1);
#pragma unroll
    for (int fd = 0; fd < 4; fd++) {
      int row = 16 * fd + (l & 15);
#pragma unroll
      for (int c = 0; c < 4; c++) {
        short8v vb = frag128(Vs, row, c * 4 + g);  // read once, used twice
        oaA[fd] = __builtin_amdgcn_mfma_f32_16x16x32_bf16(paA[c], vb, oaA[fd], 0, 0, 0);
        oaB[fd] = __builtin_amdgcn_mfma_f32_16x16x32_bf16(paB[c], vb, oaB[fd], 0, 0, 0);
      }
    }
    __builtin_amdgcn_s_setprio(0);

    if (kt < 7) {
      __syncthreads();  // all waves done reading K/V tile kt
#pragma unroll
      for (int it = 0; it < 4; it++) {
        *(short8v*)&Ks[it * 2048 + w * 512 + l * 8] = kreg[it];
        *(short8v*)&Vs[it * 2048 + w * 512 + l * 8] = vreg[it];
      }
      __syncthreads();  // tile kt+1 visible
    }
  }

  // normalize; stage O into own P slices; coalesced global write
  const float invA = 1.0f / lA, invB = 1.0f / lB;
  float ivA[4], ivB[4];
#pragma unroll
  for (int r = 0; r < 4; r++) {
    ivA[r] = __shfl(invA, 4 * g + r);
    ivB[r] = __shfl(invB, 4 * g + r);
  }
#pragma unroll
  for (int r = 0; r < 4; r++)
#pragma unroll
    for (int f = 0; f < 4; f++) {
      PsA[(4 * g + r) * 136 + 16 * f + (l & 15)] = bf16_of(oaA[f][r] * ivA[r]);
      PsB[(4 * g + r) * 136 + 16 * f + (l & 15)] = bf16_of(oaB[f][r] * ivB[r]);
    }
  __syncthreads();
  short* dst = aoT + ((size_t)b * HWn + qt * 128) * 512 + head * 64;
#pragma unroll
  for (int it = 0; it < 4; it++) {
    int r = (t >> 3) + 32 * it;  // global q-row 0..127; slice = r>>4
    int c8 = (t & 7) * 8;
    *(short8v*)&dst[(size_t)r * 512 + c8] =
        *(const short8v*)&Ps[(r >> 4) * 2176 + (r & 15) * 136 + c8];
  }
}

extern "C" void kernel_launch(void* const* d_in, const int* in_sizes, int n_in,
                              void* d_out, int out_size, void* d_ws, size_t ws_size,
                              hipStream_t stream) {
  const float* x = (const float*)d_in[0];
  const float* gn_w = (const float*)d_in[1];
  const float* gn_b = (const float*)d_in[2];
  const float* qkv_w = (const float*)d_in[3];
  const float* qkv_b = (const float*)d_in[4];
  const float* proj_w = (const float*)d_in[5];
  const float* proj_b = (const float*)d_in[6];
  float* out = (float*)d_out;

  char* ws = (char*)d_ws;
  short* wqb = (short*)(ws + 4096);            // 1536*512
  short* wpb = (short*)(ws + 4096 + 1572864);  // 512*512
  char* p = ws + 4096 + 1572864 + 524288;
  const size_t SB = (size_t)Bn * HWn * 512 * 2;  // 8 MB
  short* xn3 = (short*)p;
  short* qT = (short*)(p + SB);
  short* kT = (short*)(p + 2 * SB);
  short* vB = (short*)(p + 3 * SB);
  short* aoT = (short*)(p + 4 * SB);

  gn_fused_k<<<1280, 256, 0, stream>>>(x, gn_w, gn_b, qkv_w, proj_w, wqb, wpb, xn3);
  gemm_qkv_k<<<768, 256, 0, stream>>>(wqb, xn3, qkv_b, qT, kT, vB);
  attn_k<<<512, 256, 0, stream>>>(qT, kT, vB, aoT);
  gemm_proj_k<<<256, 512, 0, stream>>>(wpb, aoT, proj_b, x, out);
}